// Round 2
// baseline (174.683 us; speedup 1.0000x reference)
//
#include <hip/hip_runtime.h>

#define HH 512
#define WW 640
#define HP 384
#define WP 512
#define PAD 64
#define NF 16
#define HW (HH*WW)
#define PXB 128                 // pixels per block
#define NPH 8                   // phases (2 frames each)
#define NBLK (HW/PXB)           // 2560 blocks
#define CSTR 34                 // LDS stride (floats) per pixel: 32 + pad

typedef float vf2 __attribute__((ext_vector_type(2)));

__device__ __forceinline__ float ntload(const float* p) {
    return __builtin_nontemporal_load(p);
}
// nontemporal 8B load — use ext_vector_type (builtin rejects HIP_vector_type structs)
__device__ __forceinline__ vf2 ntload2(const float* p) {
    return __builtin_nontemporal_load(reinterpret_cast<const vf2*>(p));
}

// 8B load at 4B alignment — lowers to a single global_load_dwordx2 on gfx950
// (unaligned global access is HW-supported; worst case compiler splits into
// 2 dwords == status quo).
__device__ __forceinline__ vf2 ld2u(const float* __restrict__ p) {
    vf2 r;
    __builtin_memcpy(&r, p, sizeof(r));
    return r;
}

// bilinear sample of padded y_pred1[f] at raw grid coords (Cy, Cx).
// The two x-taps of each row are fused into ONE dwordx2 gather; ix is clamped
// to [0, WP-2] so the 8B access never leaves the frame, and the d-selects
// reproduce the reference's out-of-bounds zero-masking bit-exactly.
__device__ __forceinline__ float bsample(const float* __restrict__ yp, int f, float Cy, float Cx) {
    // replicate reference f32 op sequence exactly
    float gy = (Cy - 256.0f) / 256.0f;
    float gx = (Cx - 320.0f) / 320.0f;
    float y = ((gy + 1.0f) * 512.0f - 1.0f) * 0.5f;
    float x = ((gx + 1.0f) * 640.0f - 1.0f) * 0.5f;
    float y0f = floorf(y), x0f = floorf(x);
    float wy1 = y - y0f, wx1 = x - x0f;
    float wy0 = 1.0f - wy1, wx0 = 1.0f - wx1;
    int iy0 = (int)y0f - PAD;              // pad-local coords
    int ix  = (int)x0f - PAD;
    int ixc = min(max(ix, 0), WP - 2);     // clamped so [ixc, ixc+1] is in-row
    int d   = ix - ixc;                    // 0: aligned; 1: ix==WP-1; -1: ix==-1; else fully OOB

    const float* base = yp + (size_t)f * HP * WP + ixc;
    float r0 = 0.f, r1 = 0.f;
    if ((unsigned)iy0 < HP) {
        vf2 v = ld2u(base + (size_t)iy0 * WP);
        float v0 = (d == 0) ? v.x : ((d == 1)  ? v.y : 0.f);
        float v1 = (d == 0) ? v.y : ((d == -1) ? v.x : 0.f);
        r0 = wx0 * v0 + wx1 * v1;
    }
    if ((unsigned)(iy0 + 1) < HP) {
        vf2 v = ld2u(base + (size_t)(iy0 + 1) * WP);
        float v0 = (d == 0) ? v.x : ((d == 1)  ? v.y : 0.f);
        float v1 = (d == 0) ? v.y : ((d == -1) ? v.x : 0.f);
        r1 = wx0 * v0 + wx1 * v1;
    }
    return wy0 * r0 + wy1 * r1;
}

__device__ __forceinline__ void coef(const float* __restrict__ inp7,
                                     const float* __restrict__ inp77,
                                     int k, float& a, float& b, float& c) {
    if (k == 0)      { a = inp77[0] + 1.0f;  b = inp77[3];     c = inp77[6];     }
    else if (k <= 15){ a = inp7[k-1] + 1.0f; b = inp7[45+k-1]; c = inp7[90+k-1]; }
    else             { a = 1.0f;             b = 0.0f;         c = 0.0f;         }
}

__global__ __launch_bounds__(256, 4) void verloss_main(
    const float* __restrict__ y_pred,   // (15, 384, 512)
    const float* __restrict__ inp1,     // (2, H, W)
    const float* __restrict__ inp2,     // (32, H, W)
    const float* __restrict__ inp2b,    // (32, H, W)
    const float* __restrict__ inp7,     // (135)
    const float* __restrict__ inp6,     // (384, 512)
    const float* __restrict__ inp77,    // (9)
    const float* __restrict__ C,        // (H, W, 32)
    const float* __restrict__ Cb,       // (H, W, 32)
    double* __restrict__ partial)
{
    __shared__ float sC [PXB * CSTR];
    __shared__ float sCb[PXB * CSTR];
    __shared__ double sdata[4];

    const int tid  = threadIdx.x;
    const int pxl  = tid >> 1;                 // local pixel 0..127
    const int kloc = tid & 1;                  // k parity
    const int p    = blockIdx.x * PXB + pxl;   // global pixel

    // ---- stage this block's C/Cb lines into LDS (coalesced, nontemporal:
    //      touch-once streams must not evict the gather-hot y_pred from L2)
    {
        const float* gC  = C  + (size_t)blockIdx.x * PXB * 32;
        const float* gCb = Cb + (size_t)blockIdx.x * PXB * 32;
        #pragma unroll
        for (int i = 0; i < 8; ++i) {
            int f2 = tid + i * 256;            // float2 index 0..2047
            int spx = f2 >> 4, sj = f2 & 15;   // pixel, float2-within-line
            vf2 v  = ntload2(gC  + 2 * f2);
            vf2 vb = ntload2(gCb + 2 * f2);
            *reinterpret_cast<vf2*>(&sC [spx * CSTR + 2 * sj]) = v;
            *reinterpret_cast<vf2*>(&sCb[spx * CSTR + 2 * sj]) = vb;
        }
    }

    // ---- per-pixel invariants
    int y = p / WW, x = p - y * WW;
    int iy = y - PAD, ix = x - PAD;
    bool inpad = ((unsigned)iy < HP) && ((unsigned)ix < WP);
    int padoff = iy * WP + ix;                 // valid only if inpad
    float A = inp1[HW + p];                    // inp1[0,1]
    float B = inp1[p];                         // inp1[0,0]

    float acc = 0.f;
    __syncthreads();

    // No per-phase barrier: phases are independent, let the compiler
    // software-pipeline gathers across phases for MLP.
    #pragma unroll
    for (int g = 0; g < NPH; ++g) {
        int k = 2 * g + kloc;                  // frame 0..15

        float ak, bk, ck, an, bn, cn;
        coef(inp7, inp77, k,     ak, bk, ck);
        coef(inp7, inp77, k + 1, an, bn, cn);

        // direct terms (hot frames of this phase — L2 resident)
        float prev;
        if (k == 0) prev = inpad ? inp6[padoff] : 0.f;
        else        prev = inpad ? y_pred[(size_t)((k-1)*HP)*WP + padoff] : 0.f;
        float nxt = (k < NF-1 && inpad) ? y_pred[(size_t)(k*HP)*WP + padoff] : 0.f;

        // warped terms — random gathers into the phase's hot frames
        float w5 = 0.f, w6 = 0.f;
        if (k < NF-1) {
            vf2 gg = *reinterpret_cast<const vf2*>(&sC [pxl * CSTR + 2 * k]);
            w5 = bsample(y_pred, k, gg.x, gg.y);
        }
        if (k >= 1) {
            vf2 gg = *reinterpret_cast<const vf2*>(&sCb[pxl * CSTR + 2 * k]);
            w6 = bsample(y_pred, k - 1, gg.x, gg.y);
        }

        // touch-once streams — non-temporal, fully coalesced per 32-lane group
        float i2hi = ntload(inp2  + (size_t)(2*k+1)*HW + p);
        float i2lo = ntload(inp2  + (size_t)(2*k  )*HW + p);
        float ibhi = ntload(inp2b + (size_t)(2*k+1)*HW + p);
        float iblo = ntload(inp2b + (size_t)(2*k  )*HW + p);

        float d0 = ak*A + bk*B + ck + prev - (an*i2hi + bn*i2lo + cn + w5);
        float d1 = ak*ibhi + bk*iblo + ck + w6 - (an*A + bn*B + cn + nxt);
        acc += d0*d0 + d1*d1;
    }

    // ---- block reduction in double
    double v = (double)acc;
    #pragma unroll
    for (int off = 32; off > 0; off >>= 1) v += __shfl_down(v, off, 64);
    int wid = tid >> 6, lane = tid & 63;
    if (lane == 0) sdata[wid] = v;
    __syncthreads();
    if (tid == 0)
        partial[blockIdx.x] = sdata[0] + sdata[1] + sdata[2] + sdata[3];
}

__global__ __launch_bounds__(1024) void verloss_finalize(
    const double* __restrict__ partial, int n, float* __restrict__ out)
{
    double v = 0.0;
    for (int i = threadIdx.x; i < n; i += 1024) v += partial[i];
    #pragma unroll
    for (int off = 32; off > 0; off >>= 1) v += __shfl_down(v, off, 64);
    __shared__ double sdata[16];
    int wid = threadIdx.x >> 6, lane = threadIdx.x & 63;
    if (lane == 0) sdata[wid] = v;
    __syncthreads();
    if (threadIdx.x == 0) {
        double s = 0.0;
        #pragma unroll
        for (int i = 0; i < 16; ++i) s += sdata[i];
        out[0] = (float)(s * (0.5 / ((double)NF * HW)));
    }
}

extern "C" void kernel_launch(void* const* d_in, const int* in_sizes, int n_in,
                              void* d_out, int out_size, void* d_ws, size_t ws_size,
                              hipStream_t stream) {
    const float* y_pred = (const float*)d_in[0];
    const float* inp1   = (const float*)d_in[1];
    const float* inp2   = (const float*)d_in[2];
    const float* inp2b  = (const float*)d_in[3];
    const float* inp7   = (const float*)d_in[4];
    const float* inp6   = (const float*)d_in[5];
    const float* inp77  = (const float*)d_in[6];
    const float* C      = (const float*)d_in[9];
    const float* Cb     = (const float*)d_in[10];
    float* out = (float*)d_out;
    double* partial = (double*)d_ws;

    verloss_main<<<NBLK, 256, 0, stream>>>(y_pred, inp1, inp2, inp2b, inp7,
                                           inp6, inp77, C, Cb, partial);
    verloss_finalize<<<1, 1024, 0, stream>>>(partial, NBLK, out);
}

// Round 3
// 131.209 us; speedup vs baseline: 1.3313x; 1.3313x over previous
//
#include <hip/hip_runtime.h>

#define HH 512
#define WW 640
#define HP 384
#define WP 512
#define PAD 64
#define NF 16
#define HW (HH*WW)
#define PXB 128                 // pixels per block
#define NPH 8                   // phases (2 frames each)
#define NBLK (HW/PXB)           // 2560 blocks
#define CSTR 34                 // LDS stride (floats) per pixel: 32 + pad

typedef float vf2 __attribute__((ext_vector_type(2)));

__device__ __forceinline__ float ntload(const float* p) {
    return __builtin_nontemporal_load(p);
}
// nontemporal 8B load — use ext_vector_type (builtin rejects HIP_vector_type structs)
__device__ __forceinline__ vf2 ntload2(const float* p) {
    return __builtin_nontemporal_load(reinterpret_cast<const vf2*>(p));
}

// 8B load at 4B alignment — lowers to a single global_load_dwordx2 on gfx950.
__device__ __forceinline__ vf2 ld2u(const float* __restrict__ p) {
    vf2 r;
    __builtin_memcpy(&r, p, sizeof(r));
    return r;
}

// bilinear sample of padded y_pred1[f] at raw grid coords (Cy, Cx).
// The two x-taps of each row are fused into ONE dwordx2 gather; ix is clamped
// to [0, WP-2] so the 8B access never leaves the frame, and the d-selects
// reproduce the reference's out-of-bounds zero-masking bit-exactly.
__device__ __forceinline__ float bsample(const float* __restrict__ yp, int f, float Cy, float Cx) {
    // replicate reference f32 op sequence exactly
    float gy = (Cy - 256.0f) / 256.0f;
    float gx = (Cx - 320.0f) / 320.0f;
    float y = ((gy + 1.0f) * 512.0f - 1.0f) * 0.5f;
    float x = ((gx + 1.0f) * 640.0f - 1.0f) * 0.5f;
    float y0f = floorf(y), x0f = floorf(x);
    float wy1 = y - y0f, wx1 = x - x0f;
    float wy0 = 1.0f - wy1, wx0 = 1.0f - wx1;
    int iy0 = (int)y0f - PAD;              // pad-local coords
    int ix  = (int)x0f - PAD;
    int ixc = min(max(ix, 0), WP - 2);     // clamped so [ixc, ixc+1] is in-row
    int d   = ix - ixc;                    // 0: aligned; 1: ix==WP-1; -1: ix==-1; else fully OOB

    const float* base = yp + (size_t)f * HP * WP + ixc;
    float r0 = 0.f, r1 = 0.f;
    if ((unsigned)iy0 < HP) {
        vf2 v = ld2u(base + (size_t)iy0 * WP);
        float v0 = (d == 0) ? v.x : ((d == 1)  ? v.y : 0.f);
        float v1 = (d == 0) ? v.y : ((d == -1) ? v.x : 0.f);
        r0 = wx0 * v0 + wx1 * v1;
    }
    if ((unsigned)(iy0 + 1) < HP) {
        vf2 v = ld2u(base + (size_t)(iy0 + 1) * WP);
        float v0 = (d == 0) ? v.x : ((d == 1)  ? v.y : 0.f);
        float v1 = (d == 0) ? v.y : ((d == -1) ? v.x : 0.f);
        r1 = wx0 * v0 + wx1 * v1;
    }
    return wy0 * r0 + wy1 * r1;
}

__device__ __forceinline__ void coef(const float* __restrict__ inp7,
                                     const float* __restrict__ inp77,
                                     int k, float& a, float& b, float& c) {
    if (k == 0)      { a = inp77[0] + 1.0f;  b = inp77[3];     c = inp77[6];     }
    else if (k <= 15){ a = inp7[k-1] + 1.0f; b = inp7[45+k-1]; c = inp7[90+k-1]; }
    else             { a = 1.0f;             b = 0.0f;         c = 0.0f;         }
}

__global__ __launch_bounds__(256, 4) void verloss_main(
    const float* __restrict__ y_pred,   // (15, 384, 512)
    const float* __restrict__ inp1,     // (2, H, W)
    const float* __restrict__ inp2,     // (32, H, W)
    const float* __restrict__ inp2b,    // (32, H, W)
    const float* __restrict__ inp7,     // (135)
    const float* __restrict__ inp6,     // (384, 512)
    const float* __restrict__ inp77,    // (9)
    const float* __restrict__ C,        // (H, W, 32)
    const float* __restrict__ Cb,       // (H, W, 32)
    double* __restrict__ partial)
{
    __shared__ float sC [PXB * CSTR];
    __shared__ float sCb[PXB * CSTR];
    __shared__ double sdata[4];

    const int tid  = threadIdx.x;
    const int pxl  = tid >> 1;                 // local pixel 0..127
    const int kloc = tid & 1;                  // k parity
    const int p    = blockIdx.x * PXB + pxl;   // global pixel

    // ---- stage this block's C/Cb lines into LDS (coalesced, nontemporal:
    //      touch-once streams must not evict the gather-hot y_pred from L2)
    {
        const float* gC  = C  + (size_t)blockIdx.x * PXB * 32;
        const float* gCb = Cb + (size_t)blockIdx.x * PXB * 32;
        #pragma unroll
        for (int i = 0; i < 8; ++i) {
            int f2 = tid + i * 256;            // float2 index 0..2047
            int spx = f2 >> 4, sj = f2 & 15;   // pixel, float2-within-line
            vf2 v  = ntload2(gC  + 2 * f2);
            vf2 vb = ntload2(gCb + 2 * f2);
            *reinterpret_cast<vf2*>(&sC [spx * CSTR + 2 * sj]) = v;
            *reinterpret_cast<vf2*>(&sCb[spx * CSTR + 2 * sj]) = vb;
        }
    }

    // ---- per-pixel invariants
    int y = p / WW, x = p - y * WW;
    int iy = y - PAD, ix = x - PAD;
    bool inpad = ((unsigned)iy < HP) && ((unsigned)ix < WP);
    int padoff = iy * WP + ix;                 // valid only if inpad
    float A = inp1[HW + p];                    // inp1[0,1]
    float B = inp1[p];                         // inp1[0,0]

    float acc = 0.f;
    __syncthreads();

    // Phase-locked loop: the per-phase barrier keeps every warp of the block
    // gathering from the SAME ~3 y_pred frames → working set fits per-XCD L2.
    // (Round-2 measured: removing it costs +33 MB FETCH and +22% time.)
    for (int g = 0; g < NPH; ++g) {
        int k = 2 * g + kloc;                  // frame 0..15

        float ak, bk, ck, an, bn, cn;
        coef(inp7, inp77, k,     ak, bk, ck);
        coef(inp7, inp77, k + 1, an, bn, cn);

        // direct terms (hot frames of this phase — L2 resident)
        float prev;
        if (k == 0) prev = inpad ? inp6[padoff] : 0.f;
        else        prev = inpad ? y_pred[(size_t)((k-1)*HP)*WP + padoff] : 0.f;
        float nxt = (k < NF-1 && inpad) ? y_pred[(size_t)(k*HP)*WP + padoff] : 0.f;

        // warped terms — random gathers into the phase's hot frames (L2 resident)
        float w5 = 0.f, w6 = 0.f;
        if (k < NF-1) {
            vf2 gg = *reinterpret_cast<const vf2*>(&sC [pxl * CSTR + 2 * k]);
            w5 = bsample(y_pred, k, gg.x, gg.y);
        }
        if (k >= 1) {
            vf2 gg = *reinterpret_cast<const vf2*>(&sCb[pxl * CSTR + 2 * k]);
            w6 = bsample(y_pred, k - 1, gg.x, gg.y);
        }

        // touch-once streams — non-temporal, fully coalesced per 32-lane group
        float i2hi = ntload(inp2  + (size_t)(2*k+1)*HW + p);
        float i2lo = ntload(inp2  + (size_t)(2*k  )*HW + p);
        float ibhi = ntload(inp2b + (size_t)(2*k+1)*HW + p);
        float iblo = ntload(inp2b + (size_t)(2*k  )*HW + p);

        float d0 = ak*A + bk*B + ck + prev - (an*i2hi + bn*i2lo + cn + w5);
        float d1 = ak*ibhi + bk*iblo + ck + w6 - (an*A + bn*B + cn + nxt);
        acc += d0*d0 + d1*d1;

        if (g < NPH - 1) __syncthreads();      // keep block phase-locked
    }

    // ---- block reduction in double
    double v = (double)acc;
    #pragma unroll
    for (int off = 32; off > 0; off >>= 1) v += __shfl_down(v, off, 64);
    int wid = tid >> 6, lane = tid & 63;
    if (lane == 0) sdata[wid] = v;
    __syncthreads();
    if (tid == 0)
        partial[blockIdx.x] = sdata[0] + sdata[1] + sdata[2] + sdata[3];
}

__global__ __launch_bounds__(1024) void verloss_finalize(
    const double* __restrict__ partial, int n, float* __restrict__ out)
{
    double v = 0.0;
    for (int i = threadIdx.x; i < n; i += 1024) v += partial[i];
    #pragma unroll
    for (int off = 32; off > 0; off >>= 1) v += __shfl_down(v, off, 64);
    __shared__ double sdata[16];
    int wid = threadIdx.x >> 6, lane = threadIdx.x & 63;
    if (lane == 0) sdata[wid] = v;
    __syncthreads();
    if (threadIdx.x == 0) {
        double s = 0.0;
        #pragma unroll
        for (int i = 0; i < 16; ++i) s += sdata[i];
        out[0] = (float)(s * (0.5 / ((double)NF * HW)));
    }
}

extern "C" void kernel_launch(void* const* d_in, const int* in_sizes, int n_in,
                              void* d_out, int out_size, void* d_ws, size_t ws_size,
                              hipStream_t stream) {
    const float* y_pred = (const float*)d_in[0];
    const float* inp1   = (const float*)d_in[1];
    const float* inp2   = (const float*)d_in[2];
    const float* inp2b  = (const float*)d_in[3];
    const float* inp7   = (const float*)d_in[4];
    const float* inp6   = (const float*)d_in[5];
    const float* inp77  = (const float*)d_in[6];
    const float* C      = (const float*)d_in[9];
    const float* Cb     = (const float*)d_in[10];
    float* out = (float*)d_out;
    double* partial = (double*)d_ws;

    verloss_main<<<NBLK, 256, 0, stream>>>(y_pred, inp1, inp2, inp2b, inp7,
                                           inp6, inp77, C, Cb, partial);
    verloss_finalize<<<1, 1024, 0, stream>>>(partial, NBLK, out);
}